// Round 1
// baseline (134.177 us; speedup 1.0000x reference)
//
#include <hip/hip_runtime.h>
#include <math.h>

#define NB   16
#define NH   128
#define NW   128
#define NCLS 80
#define NPOS (NB * NH * NW)          // 262144 spatial positions
#define STRIDE_F 8.0f

// One thread per spatial position.
// Reads: bbox[pos][0:4], center[pos], cls_logits[pos][0:80]
// Writes: out[pos*4 .. pos*4+3] = xywh
//         out[4*NPOS + pos]     = (float)argmax_class
//         out[5*NPOS + pos]     = sqrt(sigmoid(center) * sigmoid(max_logit))
__global__ __launch_bounds__(256) void fcos_decode_kernel(
    const float* __restrict__ bbox,
    const float* __restrict__ center,
    const float* __restrict__ cls,
    float* __restrict__ out)
{
    const int pos = blockIdx.x * blockDim.x + threadIdx.x;
    if (pos >= NPOS) return;

    const int w = pos & (NW - 1);          // fastest dim
    const int h = (pos >> 7) & (NH - 1);

    // ---- bbox decode: p = exp(v) * stride, then ltrb -> xywh ----
    const float4 ltrb = *(const float4*)(bbox + (size_t)pos * 4);
    const float l = expf(ltrb.x) * STRIDE_F;
    const float t = expf(ltrb.y) * STRIDE_F;
    const float r = expf(ltrb.z) * STRIDE_F;
    const float b = expf(ltrb.w) * STRIDE_F;

    const float cx = (float)w * STRIDE_F + STRIDE_F * 0.5f;
    const float cy = (float)h * STRIDE_F + STRIDE_F * 0.5f;

    const float x  = cx - (l - r) * 0.5f;
    const float y  = cy - (t - b) * 0.5f;
    const float bw = l + r;
    const float bh = t + b;

    // ---- class max/argmax over 80 logits (sigmoid is monotonic) ----
    const float4* cp = (const float4*)(cls + (size_t)pos * NCLS);
    float best = -INFINITY;
    int   bidx = 0;
    #pragma unroll
    for (int j = 0; j < NCLS / 4; ++j) {
        const float4 v = cp[j];
        const int c = j * 4;
        if (v.x > best) { best = v.x; bidx = c;     }
        if (v.y > best) { best = v.y; bidx = c + 1; }
        if (v.z > best) { best = v.z; bidx = c + 2; }
        if (v.w > best) { best = v.w; bidx = c + 3; }
    }
    const float cls_score = 1.0f / (1.0f + expf(-best));

    // ---- centerness ----
    const float cen = 1.0f / (1.0f + expf(-center[pos]));
    const float conf = sqrtf(cen * cls_score);

    // ---- stores ----
    ((float4*)out)[pos] = make_float4(x, y, bw, bh);
    out[(size_t)4 * NPOS + pos] = (float)bidx;
    out[(size_t)5 * NPOS + pos] = conf;
}

extern "C" void kernel_launch(void* const* d_in, const int* in_sizes, int n_in,
                              void* d_out, int out_size, void* d_ws, size_t ws_size,
                              hipStream_t stream)
{
    const float* bbox   = (const float*)d_in[0];
    const float* center = (const float*)d_in[1];
    const float* cls    = (const float*)d_in[2];
    float* out = (float*)d_out;

    const int threads = 256;
    const int blocks  = (NPOS + threads - 1) / threads;  // 1024
    fcos_decode_kernel<<<blocks, threads, 0, stream>>>(bbox, center, cls, out);
}

// Round 2
// 126.554 us; speedup vs baseline: 1.0602x; 1.0602x over previous
//
#include <hip/hip_runtime.h>
#include <math.h>

#define NB   16
#define NH   128
#define NW   128
#define NCLS 80
#define NPOS (NB * NH * NW)          // 262144 spatial positions
#define STRIDE_F 8.0f

#define BLOCKS_A (NPOS / 256)        // 1024: bbox decode, 1 thread/pos
#define BLOCKS_B (NPOS / 64)         // 4096: cls reduce, 4 lanes/pos, 64 pos/block

// Output layout (flat, reference return order):
//   [0 .. 4*NPOS)        xywh, float4 per position
//   [4*NPOS .. 5*NPOS)   argmax class index (as float)
//   [5*NPOS .. 6*NPOS)   conf = sqrt(sigmoid(center)*sigmoid(max_logit))
__global__ __launch_bounds__(256) void fcos_decode_kernel(
    const float* __restrict__ bbox,
    const float* __restrict__ center,
    const float* __restrict__ cls,
    float* __restrict__ out)
{
    const int bid = blockIdx.x;

    if (bid < BLOCKS_A) {
        // ---------- Role A: bbox ltrb->xywh, fully coalesced ----------
        const int pos = bid * 256 + threadIdx.x;
        const int w = pos & (NW - 1);
        const int h = (pos >> 7) & (NH - 1);

        const float4 ltrb = ((const float4*)bbox)[pos];
        const float l = expf(ltrb.x) * STRIDE_F;
        const float t = expf(ltrb.y) * STRIDE_F;
        const float r = expf(ltrb.z) * STRIDE_F;
        const float b = expf(ltrb.w) * STRIDE_F;

        const float cx = (float)w * STRIDE_F + STRIDE_F * 0.5f;
        const float cy = (float)h * STRIDE_F + STRIDE_F * 0.5f;

        ((float4*)out)[pos] = make_float4(cx - (l - r) * 0.5f,
                                          cy - (t - b) * 0.5f,
                                          l + r,
                                          t + b);
    } else {
        // ---------- Role B: class max/argmax + centerness conf ----------
        // 4 lanes per position; lane q covers classes [q*20, q*20+20).
        const int b    = bid - BLOCKS_A;
        const int wave = threadIdx.x >> 6;
        const int lane = threadIdx.x & 63;
        const int p    = lane >> 2;          // 0..15 position within wave
        const int q    = lane & 3;           // 0..3 class chunk
        const int pos  = b * 64 + wave * 16 + p;

        // 80 B per lane, 5 KB contiguous per wave — every line fully used.
        const float4* cp = (const float4*)(cls + (size_t)pos * NCLS + q * 20);
        const float4 v0 = cp[0];
        const float4 v1 = cp[1];
        const float4 v2 = cp[2];
        const float4 v3 = cp[3];
        const float4 v4 = cp[4];

        float best = v0.x; int li = 0;
        #define SCAN(val, j) if ((val) > best) { best = (val); li = (j); }
        SCAN(v0.y, 1)  SCAN(v0.z, 2)  SCAN(v0.w, 3)
        SCAN(v1.x, 4)  SCAN(v1.y, 5)  SCAN(v1.z, 6)  SCAN(v1.w, 7)
        SCAN(v2.x, 8)  SCAN(v2.y, 9)  SCAN(v2.z, 10) SCAN(v2.w, 11)
        SCAN(v3.x, 12) SCAN(v3.y, 13) SCAN(v3.z, 14) SCAN(v3.w, 15)
        SCAN(v4.x, 16) SCAN(v4.y, 17) SCAN(v4.z, 18) SCAN(v4.w, 19)
        #undef SCAN
        int idx = q * 20 + li;

        // Butterfly over the 4-lane group; first-occurrence tie-break.
        #pragma unroll
        for (int mask = 1; mask <= 2; mask <<= 1) {
            const float ov = __shfl_xor(best, mask);
            const int   oi = __shfl_xor(idx,  mask);
            if (ov > best || (ov == best && oi < idx)) { best = ov; idx = oi; }
        }

        if (q == 0) {
            // 16 active lanes read/write 64 contiguous bytes each — coalesced.
            const float cen  = center[pos];
            const float sc   = 1.0f / (1.0f + expf(-cen));
            const float ss   = 1.0f / (1.0f + expf(-best));
            out[(size_t)4 * NPOS + pos] = (float)idx;
            out[(size_t)5 * NPOS + pos] = sqrtf(sc * ss);
        }
    }
}

extern "C" void kernel_launch(void* const* d_in, const int* in_sizes, int n_in,
                              void* d_out, int out_size, void* d_ws, size_t ws_size,
                              hipStream_t stream)
{
    const float* bbox   = (const float*)d_in[0];
    const float* center = (const float*)d_in[1];
    const float* cls    = (const float*)d_in[2];
    float* out = (float*)d_out;

    fcos_decode_kernel<<<BLOCKS_A + BLOCKS_B, 256, 0, stream>>>(bbox, center, cls, out);
}